// Round 5
// baseline (114.485 us; speedup 1.0000x reference)
//
#include <hip/hip_runtime.h>

// Shapes fixed by setup_inputs(): B=8, C=256, H=128, W=128
#define B_ 8
#define C_ 256
#define H_ 128
#define W_ 128
#define N_TOTAL (B_ * C_ * H_ * W_)      // 33,554,432 floats per tensor
#define N_VEC   (N_TOTAL / 4)            // 8,388,608 float4
#define NB1     2048
#define NT1     256
#define GSTRIDE (NB1 * NT1)              // 524,288 threads
#define ITERS   (N_VEC / GSTRIDE)        // 16 exactly
#define NSAMP   64
#define NB2     (B_ * NSAMP)             // 512

typedef float f4 __attribute__((ext_vector_type(4)));

// Single fused kernel:
//  - all 2048 blocks: slice of the grand dot product -> partial1[blk]
//  - blocks 0..511, wave 0: one sim dot each -> partial2[blk]
//  - last block to finish (device-scope atomic counter): reduce all partials
//    in a FIXED order (deterministic) and write the scalar.
__global__ __launch_bounds__(NT1) void fused_all_kernel(
    const f4* __restrict__ q, const f4* __restrict__ t,
    const int* __restrict__ idx1, const int* __restrict__ idx2,
    float* __restrict__ partial1, float* __restrict__ partial2,
    unsigned int* __restrict__ counter, float* __restrict__ out) {
    int blk = blockIdx.x;

    // ---- fused sim: sim[b,n] = relu( sum_w T[b,idx1[n],w] * T[7-b,idx2[n],w] )
    if (blk < NB2 && threadIdx.x < 64) {
        const float* tf = (const float*)t;
        int b = blk >> 6;
        int n = blk & (NSAMP - 1);
        const float* p1 = tf + ((size_t)b * (C_ * H_) + idx1[n]) * W_;
        const float* p2 = tf + ((size_t)(B_ - 1 - b) * (C_ * H_) + idx2[n]) * W_;
        int lane = threadIdx.x;
        float acc = p1[lane] * p2[lane] + p1[lane + 64] * p2[lane + 64];
        #pragma unroll
        for (int off = 32; off > 0; off >>= 1) acc += __shfl_down(acc, off, 64);
        if (lane == 0) partial2[blk] = fmaxf(acc, 0.0f);
    }

    // ---- grand dot slice: x4 unroll, 4 independent accumulators
    int tid = blk * NT1 + threadIdx.x;
    float acc0 = 0.f, acc1 = 0.f, acc2 = 0.f, acc3 = 0.f;
    #pragma unroll
    for (int j = 0; j < ITERS; j += 4) {
        f4 qa = q[tid + (size_t)(j + 0) * GSTRIDE];
        f4 qb = q[tid + (size_t)(j + 1) * GSTRIDE];
        f4 qc = q[tid + (size_t)(j + 2) * GSTRIDE];
        f4 qd = q[tid + (size_t)(j + 3) * GSTRIDE];
        f4 ta = t[tid + (size_t)(j + 0) * GSTRIDE];
        f4 tb = t[tid + (size_t)(j + 1) * GSTRIDE];
        f4 tc = t[tid + (size_t)(j + 2) * GSTRIDE];
        f4 td = t[tid + (size_t)(j + 3) * GSTRIDE];
        acc0 += qa.x * ta.x + qa.y * ta.y + qa.z * ta.z + qa.w * ta.w;
        acc1 += qb.x * tb.x + qb.y * tb.y + qb.z * tb.z + qb.w * tb.w;
        acc2 += qc.x * tc.x + qc.y * tc.y + qc.z * tc.z + qc.w * tc.w;
        acc3 += qd.x * td.x + qd.y * td.y + qd.z * td.z + qd.w * td.w;
    }
    float acc = (acc0 + acc1) + (acc2 + acc3);

    #pragma unroll
    for (int off = 32; off > 0; off >>= 1) acc += __shfl_down(acc, off, 64);
    __shared__ float s[NT1 / 64];
    int wid = threadIdx.x >> 6;
    int lane = threadIdx.x & 63;
    if (lane == 0) s[wid] = acc;
    __syncthreads();

    // ---- last-block-done reduction (device-scope; deterministic sum order)
    __shared__ bool s_last;
    if (threadIdx.x == 0) {
        float blocksum = s[0] + s[1] + s[2] + s[3];
        partial1[blk] = blocksum;
        __threadfence();                       // publish partials (device scope)
        unsigned int old = atomicAdd(counter, 1u);
        s_last = (old == NB1 - 1);
    }
    __syncthreads();
    if (!s_last) return;

    __threadfence();                           // acquire all blocks' partials
    float a = 0.0f;
    for (int i = threadIdx.x; i < NB1; i += NT1) a += partial1[i];
    float b = 0.0f;
    for (int i = threadIdx.x; i < NB2; i += NT1) b += partial2[i];
    #pragma unroll
    for (int off = 32; off > 0; off >>= 1) {
        a += __shfl_down(a, off, 64);
        b += __shfl_down(b, off, 64);
    }
    __shared__ float sa[4], sb[4];
    if (lane == 0) { sa[wid] = a; sb[wid] = b; }
    __syncthreads();
    if (threadIdx.x == 0) {
        float A  = sa[0] + sa[1] + sa[2] + sa[3];
        float Bs = sb[0] + sb[1] + sb[2] + sb[3];
        out[0] = 1.0f - A / (float)(B_ * H_ * W_) + Bs / (float)NB2;
    }
}

extern "C" void kernel_launch(void* const* d_in, const int* in_sizes, int n_in,
                              void* d_out, int out_size, void* d_ws, size_t ws_size,
                              hipStream_t stream) {
    const float* query  = (const float*)d_in[0];
    const float* target = (const float*)d_in[1];
    const int*   idx1   = (const int*)d_in[2];
    const int*   idx2   = (const int*)d_in[3];
    float* out = (float*)d_out;

    float* partial1 = (float*)d_ws;                       // NB1 floats
    float* partial2 = partial1 + NB1;                     // NB2 floats
    unsigned int* counter = (unsigned int*)(partial2 + NB2);

    // counter starts poisoned (0xAA..) and is not re-poisoned between replays:
    // reset it every call with a tiny memset node (graph-capture safe).
    hipMemsetAsync(counter, 0, sizeof(unsigned int), stream);

    fused_all_kernel<<<NB1, NT1, 0, stream>>>(
        (const f4*)query, (const f4*)target, idx1, idx2,
        partial1, partial2, counter, out);
}

// Round 6
// 49.826 us; speedup vs baseline: 2.2977x; 2.2977x over previous
//
#include <hip/hip_runtime.h>

// Shapes fixed by setup_inputs(): B=8, C=256, H=128, W=128
#define B_ 8
#define C_ 256
#define H_ 128
#define W_ 128
#define N_TOTAL (B_ * C_ * H_ * W_)      // 33,554,432 floats per tensor
#define N_VEC   (N_TOTAL / 4)            // 8,388,608 float4
#define NB1     4096
#define NT1     256
#define ITERS   (N_VEC / (NB1 * NT1))    // 8 exactly
#define BLK_SPAN (NT1 * ITERS)           // 2048 f4 per block (32 KB contiguous)
#define NSAMP   64
#define NB2     (B_ * NSAMP)             // 512

typedef float f4 __attribute__((ext_vector_type(4)));

// Main kernel: grand dot product, per-block CONTIGUOUS streaming
// (block b owns f4 range [b*BLK_SPAN, (b+1)*BLK_SPAN), wave-coalesced inside).
// Sim dots fused into wave 0 of the first 512 blocks.
__global__ __launch_bounds__(NT1) void fused_main_kernel(
    const f4* __restrict__ q, const f4* __restrict__ t,
    const int* __restrict__ idx1, const int* __restrict__ idx2,
    float* __restrict__ partial1, float* __restrict__ partial2) {
    int blk = blockIdx.x;

    // ---- fused sim: sim[b,n] = relu( sum_w T[b,idx1[n],w] * T[7-b,idx2[n],w] )
    if (blk < NB2 && threadIdx.x < 64) {
        const float* tf = (const float*)t;
        int b = blk >> 6;
        int n = blk & (NSAMP - 1);
        const float* p1 = tf + ((size_t)b * (C_ * H_) + idx1[n]) * W_;
        const float* p2 = tf + ((size_t)(B_ - 1 - b) * (C_ * H_) + idx2[n]) * W_;
        int lane = threadIdx.x;
        float acc = p1[lane] * p2[lane] + p1[lane + 64] * p2[lane + 64];
        #pragma unroll
        for (int off = 32; off > 0; off >>= 1) acc += __shfl_down(acc, off, 64);
        if (lane == 0) partial2[blk] = fmaxf(acc, 0.0f);
    }

    // ---- grand dot slice: contiguous per-block stream, 4 indep accumulators
    size_t base = (size_t)blk * BLK_SPAN + threadIdx.x;
    float acc0 = 0.f, acc1 = 0.f, acc2 = 0.f, acc3 = 0.f;
    #pragma unroll
    for (int j = 0; j < ITERS; j += 4) {
        f4 qa = q[base + (j + 0) * NT1];
        f4 qb = q[base + (j + 1) * NT1];
        f4 qc = q[base + (j + 2) * NT1];
        f4 qd = q[base + (j + 3) * NT1];
        f4 ta = t[base + (j + 0) * NT1];
        f4 tb = t[base + (j + 1) * NT1];
        f4 tc = t[base + (j + 2) * NT1];
        f4 td = t[base + (j + 3) * NT1];
        acc0 += qa.x * ta.x + qa.y * ta.y + qa.z * ta.z + qa.w * ta.w;
        acc1 += qb.x * tb.x + qb.y * tb.y + qb.z * tb.z + qb.w * tb.w;
        acc2 += qc.x * tc.x + qc.y * tc.y + qc.z * tc.z + qc.w * tc.w;
        acc3 += qd.x * td.x + qd.y * td.y + qd.z * td.z + qd.w * td.w;
    }
    float acc = (acc0 + acc1) + (acc2 + acc3);

    // wave butterfly reduce then cross-wave via LDS
    #pragma unroll
    for (int off = 32; off > 0; off >>= 1) acc += __shfl_down(acc, off, 64);
    __shared__ float s[NT1 / 64];
    int wid = threadIdx.x >> 6;
    int lane = threadIdx.x & 63;
    if (lane == 0) s[wid] = acc;
    __syncthreads();
    if (threadIdx.x == 0) {
        float blocksum = 0.0f;
        #pragma unroll
        for (int w = 0; w < NT1 / 64; ++w) blocksum += s[w];
        partial1[blk] = blocksum;
    }
}

// Finalize: combine 4096 + 512 partials -> scalar (deterministic order)
__global__ __launch_bounds__(256) void finalize_kernel(
    const float* __restrict__ p1, const float* __restrict__ p2,
    float* __restrict__ out) {
    float a = 0.0f;
    for (int i = threadIdx.x; i < NB1; i += 256) a += p1[i];
    float b = 0.0f;
    for (int i = threadIdx.x; i < NB2; i += 256) b += p2[i];
    #pragma unroll
    for (int off = 32; off > 0; off >>= 1) {
        a += __shfl_down(a, off, 64);
        b += __shfl_down(b, off, 64);
    }
    __shared__ float sa[4], sb[4];
    int wid = threadIdx.x >> 6;
    int lane = threadIdx.x & 63;
    if (lane == 0) { sa[wid] = a; sb[wid] = b; }
    __syncthreads();
    if (threadIdx.x == 0) {
        float A  = sa[0] + sa[1] + sa[2] + sa[3];
        float Bs = sb[0] + sb[1] + sb[2] + sb[3];
        out[0] = 1.0f - A / (float)(B_ * H_ * W_) + Bs / (float)NB2;
    }
}

extern "C" void kernel_launch(void* const* d_in, const int* in_sizes, int n_in,
                              void* d_out, int out_size, void* d_ws, size_t ws_size,
                              hipStream_t stream) {
    const float* query  = (const float*)d_in[0];
    const float* target = (const float*)d_in[1];
    const int*   idx1   = (const int*)d_in[2];
    const int*   idx2   = (const int*)d_in[3];
    float* out = (float*)d_out;

    float* partial1 = (float*)d_ws;              // NB1 floats
    float* partial2 = partial1 + NB1;            // NB2 floats

    fused_main_kernel<<<NB1, NT1, 0, stream>>>(
        (const f4*)query, (const f4*)target, idx1, idx2,
        partial1, partial2);
    finalize_kernel<<<1, 256, 0, stream>>>(partial1, partial2, out);
}